// Round 6
// baseline (2240.886 us; speedup 1.0000x reference)
//
#include <hip/hip_runtime.h>
#include <hip/hip_bf16.h>

#define N_ROWS 131072
#define DIM 64
#define K_CODES 1024
#define KSPLIT 4
#define KSEG (K_CODES / KSPLIT)   // 256 codes per wave
#define RPB 64                    // rows per block

typedef float v2f __attribute__((ext_vector_type(2)));

// ws layout (floats): [0 .. K_CODES-1] = esq[k], [K_CODES] = loss accumulator

// esq[k] = np.sum(e*e, axis=1) with numpy's pairwise 8-accumulator order.
__global__ void vq_prep(const float* __restrict__ emb, float* __restrict__ ws) {
#pragma clang fp contract(off)
    int k = blockIdx.x * blockDim.x + threadIdx.x;
    if (k < K_CODES) {
        const float* e = emb + (size_t)k * DIM;
        float ee[DIM];
        #pragma unroll
        for (int d = 0; d < DIM; ++d) ee[d] = e[d] * e[d];
        float r[8];
        #pragma unroll
        for (int j = 0; j < 8; ++j) r[j] = ee[j];
        #pragma unroll
        for (int i = 8; i < DIM; i += 8)
            #pragma unroll
            for (int j = 0; j < 8; ++j) r[j] = r[j] + ee[i + j];
        ws[k] = ((r[0] + r[1]) + (r[2] + r[3])) + ((r[4] + r[5]) + (r[6] + r[7]));
    }
    if (blockIdx.x == 0 && threadIdx.x == 0) ws[K_CODES] = 0.f;
}

// one 16-elem chunk of the numpy einsum chain: blocks in order 12,8,4,0,
// unfused v_pk_mul then v_pk_add (per-lane IEEE identical to scalar mul/add).
#define C16(B, f0, c)                                                              \
    {                                                                              \
        _Pragma("unroll")                                                          \
        for (int b = 12; b >= 0; b -= 4) {                                         \
            const int d = (c) + b;                                                 \
            const float4 ev = (B)[(f0) + (b >> 2)];                                \
            v2f ea_ = v2f{ev.x, ev.y};                                             \
            v2f eb_ = v2f{ev.z, ev.w};                                             \
            v2f pa, pb;                                                            \
            asm("v_pk_mul_f32 %0, %1, %2" : "=v"(pa) : "v"(ea_), "v"(xv2[(d >> 1)]));      \
            asm("v_pk_mul_f32 %0, %1, %2" : "=v"(pb) : "v"(eb_), "v"(xv2[(d >> 1) + 1]));  \
            asm("v_pk_add_f32 %0, %1, %0" : "+v"(accA) : "v"(pa));                 \
            asm("v_pk_add_f32 %0, %1, %0" : "+v"(accB) : "v"(pb));                 \
        }                                                                          \
    }

// even half of code: chunks c=0,16 (fresh accumulators)
#define CEVEN(B)                                                                   \
    {                                                                              \
        accA = v2f{0.f, 0.f};                                                      \
        accB = v2f{0.f, 0.f};                                                      \
        C16(B, 0, 0) C16(B, 4, 16)                                                 \
    }

// odd half: chunks c=32,48, then distance + first-min argmin
#define CODD(B, qs, kk)                                                            \
    {                                                                              \
        C16(B, 0, 32) C16(B, 4, 48)                                                \
        float dot = (accA.x + accA.y) + (accB.x + accB.y);                         \
        float t = xsq + (qs);        /* fl(xsq + esq) */                           \
        float dist = t - 2.0f * dot; /* fl(t - fl(2*dot)); 2*dot exact */          \
        if (dist < best) { best = dist; bidx = (kk); }                             \
    }

// prefetch half h (32 floats of emb + its code's esq) into a register slot
#define PF(h, B, q)                                                                \
    {                                                                              \
        const float4* src_ = ep4 + (size_t)(h) * 8;                                \
        _Pragma("unroll")                                                          \
        for (int i_ = 0; i_ < 8; ++i_) (B)[i_] = src_[i_];                         \
        (q) = esqv[(h) >> 1];                                                      \
    }

__global__ __launch_bounds__(256, 3) void vq_main(const float* __restrict__ x,
                                                  const float* __restrict__ emb,
                                                  const float* __restrict__ ws,
                                                  float* __restrict__ out,
                                                  float* __restrict__ loss_acc) {
#pragma clang fp contract(off)
    const int lane = threadIdx.x & 63;
    const int w = __builtin_amdgcn_readfirstlane((int)(threadIdx.x >> 6));
    const int row = blockIdx.x * RPB + lane;
    const int kbase = w * KSEG;

    // e + esq stream via per-lane VMEM at wave-uniform addresses.
    // asm-obfuscate the bases so the compiler cannot prove uniformity and
    // fall back to s_load (SMEM = out-of-order returns = lgkmcnt(0) drains).
    unsigned long long ea = (unsigned long long)(emb + (size_t)kbase * DIM);
    unsigned long long qa = (unsigned long long)(ws + kbase);
    asm("" : "+v"(ea));
    asm("" : "+v"(qa));
    const float4* ep4 = (const float4*)ea;
    const float* esqv = (const float*)qa;

    // 3-slot register ring, half-code (32 floats) granularity
    float4 B0[8], B1[8], B2[8];
    float q0s, q1s, q2s;

    PF(0, B0, q0s)    // prologue: 2 halves in flight before x-load/xsq
    PF(1, B1, q1s)

    // x row in register pairs
    v2f xv2[DIM / 2];
    const float4* xp = reinterpret_cast<const float4*>(x + (size_t)row * DIM);
    #pragma unroll
    for (int i = 0; i < DIM / 4; ++i) {
        float4 v = xp[i];
        xv2[2 * i + 0] = v2f{v.x, v.y};
        xv2[2 * i + 1] = v2f{v.z, v.w};
    }

    // xsq = np.sum(x*x): elementwise square then pairwise 8-accumulator
    float xsq;
    {
        float xx[DIM];
        #pragma unroll
        for (int i = 0; i < DIM / 2; ++i) {
            xx[2 * i + 0] = xv2[i].x * xv2[i].x;
            xx[2 * i + 1] = xv2[i].y * xv2[i].y;
        }
        float r[8];
        #pragma unroll
        for (int j = 0; j < 8; ++j) r[j] = xx[j];
        #pragma unroll
        for (int i = 8; i < DIM; i += 8)
            #pragma unroll
            for (int j = 0; j < 8; ++j) r[j] = r[j] + xx[i + j];
        xsq = ((r[0] + r[1]) + (r[2] + r[3])) + ((r[4] + r[5]) + (r[6] + r[7]));
    }

    v2f accA, accB;
    float best = INFINITY;
    int bidx = 0;

    // 512 halves; 6-half unroll => fixed (slot, parity) mapping:
    //   h0+0: slot0 even | h0+1: slot1 odd | h0+2: slot2 even
    //   h0+3: slot0 odd  | h0+4: slot1 even| h0+5: slot2 odd
    // prefetch distance = 2 halves; max prefetch = 6*84+7 = 511 (never OOB)
    for (int it = 0; it < 85; ++it) {
        const int h0 = it * 6;
        const int k0 = kbase + (h0 >> 1);
        PF(h0 + 2, B2, q2s) CEVEN(B0)
        PF(h0 + 3, B0, q0s) CODD(B1, q1s, k0)
        PF(h0 + 4, B1, q1s) CEVEN(B2)
        PF(h0 + 5, B2, q2s) CODD(B0, q0s, k0 + 1)
        PF(h0 + 6, B0, q0s) CEVEN(B1)
        PF(h0 + 7, B1, q1s) CODD(B2, q2s, k0 + 2)
    }
    // tail: halves 510 (slot0, even) and 511 (slot1, odd), already prefetched
    CEVEN(B0)
    CODD(B1, q1s, kbase + KSEG - 1)

    // combine the 4 segments per row via LDS, in segment order (lowest k wins ties)
    __shared__ float sdist[KSPLIT][RPB];
    __shared__ int   sidx[KSPLIT][RPB];
    sdist[w][lane] = best;
    sidx[w][lane]  = bidx;
    __syncthreads();

    if (w == 0) {
        float bestAll = sdist[0][lane];
        int   idxAll  = sidx[0][lane];
        #pragma unroll
        for (int s = 1; s < KSPLIT; ++s) {
            float ds_ = sdist[s][lane];
            int   is_ = sidx[s][lane];
            if (ds_ < bestAll) { bestAll = ds_; idxAll = is_; }
        }

        // epilogue (wave 0 owns all 64 rows; xv2 still in regs, static indexing)
        const float* qv = emb + (size_t)idxAll * DIM;
        float* orow = out + (size_t)row * DIM;
        float lsum = 0.f;
        #pragma unroll
        for (int i = 0; i < DIM / 2; ++i) {
            const int d = 2 * i;
            float e0 = qv[d + 0], e1 = qv[d + 1];
            float df0 = e0 - xv2[i].x;
            float df1 = e1 - xv2[i].y;
            lsum = fmaf(df0, df0, lsum);
            lsum = fmaf(df1, df1, lsum);
            v2f o;
            o.x = xv2[i].x + df0;   // x + (q - x), reference op order
            o.y = xv2[i].y + df1;
            *reinterpret_cast<v2f*>(orow + d) = o;
        }

        out[(size_t)N_ROWS * DIM + row] = (float)idxAll;

        #pragma unroll
        for (int off = 32; off > 0; off >>= 1) lsum += __shfl_down(lsum, off, 64);
        if (lane == 0) atomicAdd(loss_acc, lsum);
    }
}

__global__ void vq_final(const float* __restrict__ loss_acc, float* __restrict__ out_loss) {
    if (threadIdx.x == 0 && blockIdx.x == 0) {
        float mean = loss_acc[0] / (float)((size_t)N_ROWS * DIM);
        out_loss[0] = mean;
    }
}

extern "C" void kernel_launch(void* const* d_in, const int* in_sizes, int n_in,
                              void* d_out, int out_size, void* d_ws, size_t ws_size,
                              hipStream_t stream) {
    const float* x   = (const float*)d_in[0];
    const float* emb = (const float*)d_in[1];
    float* out = (float*)d_out;
    float* ws = (float*)d_ws;

    vq_prep<<<dim3((K_CODES + 255) / 256), dim3(256), 0, stream>>>(emb, ws);
    vq_main<<<dim3(N_ROWS / RPB), dim3(256), 0, stream>>>(x, emb, ws, out, ws + K_CODES);
    vq_final<<<dim3(1), dim3(1), 0, stream>>>(ws + K_CODES,
                                              out + (size_t)N_ROWS * DIM + N_ROWS);
}

// Round 7
// 239.864 us; speedup vs baseline: 9.3423x; 9.3423x over previous
//
#include <hip/hip_runtime.h>
#include <hip/hip_bf16.h>

#define N_ROWS 131072
#define DIM 64
#define K_CODES 1024
#define NTILES (K_CODES / 16)   // 64 code-tiles of 16
#define MARGIN 4e-5f
#define LIST_CAP 65536

typedef short short8 __attribute__((ext_vector_type(8)));
typedef float f32x4 __attribute__((ext_vector_type(4)));
typedef float v2f __attribute__((ext_vector_type(2)));

__device__ __forceinline__ unsigned short f2bf(float f) {
    unsigned u = __float_as_uint(f);
    return (unsigned short)((u + 0x7fffu + ((u >> 16) & 1u)) >> 16);  // RNE
}
__device__ __forceinline__ float bf2f(unsigned short h) {
    return __uint_as_float(((unsigned)h) << 16);
}

// ws: [0]=cnt u32, [1]=loss f32, [4..1027]=esq f32, byte 8192: B panel (512KB bf16),
//     byte 532480: fixup list u32[65536]

// prep: np-exact esq + bf16 hi/lo split packed into MFMA B-fragment layout.
// B chunk c pairs with A chunk order [xh0,xh1,xl0,xl1,xh0,xh1,xl0,xl1]:
//   B[c] = eh for c in {0,1,6,7}, el for {2,3,4,5}; dim offset = (c&1)*32.
// Within chunk: lane l = g*16+n holds k-elems j=0..7 -> value src[off+g*8+j].
__global__ void vq_prep(const float* __restrict__ emb, float* __restrict__ esq,
                        unsigned short* __restrict__ wsB,
                        unsigned int* __restrict__ cnt, float* __restrict__ loss) {
#pragma clang fp contract(off)
    const int k = blockIdx.x * blockDim.x + threadIdx.x;
    if (k == 0) { *cnt = 0u; *loss = 0.f; }
    if (k >= K_CODES) return;
    const float* e = emb + (size_t)k * DIM;
    float ev[DIM];
    #pragma unroll
    for (int i = 0; i < DIM / 4; ++i) {
        float4 v = reinterpret_cast<const float4*>(e)[i];
        ev[4*i+0] = v.x; ev[4*i+1] = v.y; ev[4*i+2] = v.z; ev[4*i+3] = v.w;
    }
    {   // np-exact esq (elementwise square, pairwise 8-acc — R3-verified chain)
        float ee[DIM];
        #pragma unroll
        for (int d = 0; d < DIM; ++d) ee[d] = ev[d] * ev[d];
        float r[8];
        #pragma unroll
        for (int j = 0; j < 8; ++j) r[j] = ee[j];
        #pragma unroll
        for (int i = 8; i < DIM; i += 8)
            #pragma unroll
            for (int j = 0; j < 8; ++j) r[j] = r[j] + ee[i + j];
        esq[k] = ((r[0]+r[1]) + (r[2]+r[3])) + ((r[4]+r[5]) + (r[6]+r[7]));
    }
    unsigned short hi[DIM], lo[DIM];
    #pragma unroll
    for (int d = 0; d < DIM; ++d) {
        hi[d] = f2bf(ev[d]);
        lo[d] = f2bf(ev[d] - bf2f(hi[d]));
    }
    const int tile = k >> 4, n = k & 15;
    #pragma unroll
    for (int c = 0; c < 8; ++c) {
        const unsigned short* src = (c < 2 || c >= 6) ? hi : lo;
        const int off = (c & 1) * 32;
        #pragma unroll
        for (int g = 0; g < 4; ++g) {
            short8 s;
            #pragma unroll
            for (int j = 0; j < 8; ++j) s[j] = (short)src[off + g*8 + j];
            *reinterpret_cast<short8*>(wsB + ((size_t)((tile*8 + c)*64 + g*16 + n)) * 8) = s;
        }
    }
}

__global__ __launch_bounds__(256, 3) void vq_mfma(const float* __restrict__ x,
        const float* __restrict__ emb, const float* __restrict__ esq,
        const unsigned short* __restrict__ wsB, float* __restrict__ out,
        unsigned int* __restrict__ cnt, unsigned int* __restrict__ list,
        float* __restrict__ loss) {
    const int tid = threadIdx.x;
    const int lane = tid & 63;
    const int w = tid >> 6;
    const int g = lane >> 4, res = lane & 15;
    const int rowbase = blockIdx.x * 128 + w * 32;

    // A-frags: lane holds row (rowbase + rg*16 + res), k-slots g*8+j (self-
    // consistent with B packing -> any shared internal k-map gives correct dot)
    short8 Ah[2][2], Al[2][2];
    #pragma unroll
    for (int rg = 0; rg < 2; ++rg) {
        const float* xr = x + (size_t)(rowbase + rg*16 + res) * DIM;
        #pragma unroll
        for (int h = 0; h < 2; ++h) {
            float4 v0 = *reinterpret_cast<const float4*>(xr + h*32 + g*8);
            float4 v1 = *reinterpret_cast<const float4*>(xr + h*32 + g*8 + 4);
            float xv[8] = {v0.x, v0.y, v0.z, v0.w, v1.x, v1.y, v1.z, v1.w};
            short8 sh, sl;
            #pragma unroll
            for (int j = 0; j < 8; ++j) {
                unsigned short hb = f2bf(xv[j]);
                sh[j] = (short)hb;
                sl[j] = (short)f2bf(xv[j] - bf2f(hb));
            }
            Ah[rg][h] = sh; Al[rg][h] = sl;
        }
    }

    float b1[8], b2[8]; int bi[8];
    #pragma unroll
    for (int s = 0; s < 8; ++s) { b1[s] = 1e30f; b2[s] = 1e30f; bi[s] = 0; }

    for (int ct = 0; ct < NTILES; ++ct) {
        short8 B[8];
        const unsigned short* bp = wsB + ((size_t)(ct*8) * 64 + lane) * 8;
        #pragma unroll
        for (int c = 0; c < 8; ++c)
            B[c] = *reinterpret_cast<const short8*>(bp + (size_t)c * 64 * 8);
        const float esqv = esq[ct*16 + res];
        const int kcur = ct*16 + res;
        #pragma unroll
        for (int rg = 0; rg < 2; ++rg) {
            f32x4 C = {0.f, 0.f, 0.f, 0.f};
            C = __builtin_amdgcn_mfma_f32_16x16x32_bf16(Ah[rg][0], B[0], C, 0,0,0);
            C = __builtin_amdgcn_mfma_f32_16x16x32_bf16(Ah[rg][1], B[1], C, 0,0,0);
            C = __builtin_amdgcn_mfma_f32_16x16x32_bf16(Al[rg][0], B[2], C, 0,0,0);
            C = __builtin_amdgcn_mfma_f32_16x16x32_bf16(Al[rg][1], B[3], C, 0,0,0);
            C = __builtin_amdgcn_mfma_f32_16x16x32_bf16(Ah[rg][0], B[4], C, 0,0,0);
            C = __builtin_amdgcn_mfma_f32_16x16x32_bf16(Ah[rg][1], B[5], C, 0,0,0);
            C = __builtin_amdgcn_mfma_f32_16x16x32_bf16(Al[rg][0], B[6], C, 0,0,0);
            C = __builtin_amdgcn_mfma_f32_16x16x32_bf16(Al[rg][1], B[7], C, 0,0,0);
            #pragma unroll
            for (int r = 0; r < 4; ++r) {
                float v = fmaf(-2.0f, C[r], esqv);   // d~ = esq - 2*dot (xsq const/row)
                const int s = rg*4 + r;
                bool lt = v < b1[s];
                b2[s] = lt ? b1[s] : fminf(b2[s], v);
                b1[s] = fminf(b1[s], v);
                bi[s] = lt ? kcur : bi[s];
            }
        }
    }

    // top-2 merge across the 16 code-residue lanes (low 4 lane bits)
    #pragma unroll
    for (int m = 1; m < 16; m <<= 1) {
        #pragma unroll
        for (int s = 0; s < 8; ++s) {
            float ob1 = __shfl_xor(b1[s], m, 64);
            float ob2 = __shfl_xor(b2[s], m, 64);
            int   obi = __shfl_xor(bi[s], m, 64);
            float nb2 = fminf(fmaxf(b1[s], ob1), fminf(b2[s], ob2));
            bi[s] = (ob1 < b1[s]) ? obi : bi[s];
            b1[s] = fminf(b1[s], ob1);
            b2[s] = nb2;
        }
    }

    __shared__ int s_idx[128];
    __shared__ int s_flag[128];
    if (res == 0) {
        #pragma unroll
        for (int s = 0; s < 8; ++s) {   // row_local = w*32 + rg*16 + g*4 + r
            const int rl = w*32 + (s >> 2)*16 + g*4 + (s & 3);
            s_idx[rl] = bi[s];
            s_flag[rl] = (b2[s] - b1[s] < MARGIN) ? 1 : 0;
        }
    }
    __syncthreads();

    // epilogue: 2 threads per row (32 dims each)
    const int rl = tid >> 1, half = tid & 1;
    const int row = blockIdx.x * 128 + rl;
    const int idx = s_idx[rl];
    float lsum = 0.f;
    if (s_flag[rl]) {
        if (half == 0) {
            unsigned slot = atomicAdd(cnt, 1u);
            if (slot < LIST_CAP) list[slot] = (unsigned)row;
        }
    } else {
        const float* xr = x + (size_t)row * DIM + half*32;
        const float* qr = emb + (size_t)idx * DIM + half*32;
        float* orow = out + (size_t)row * DIM + half*32;
        #pragma unroll
        for (int i = 0; i < 8; ++i) {
            float4 xv = reinterpret_cast<const float4*>(xr)[i];
            float4 qv = reinterpret_cast<const float4*>(qr)[i];
            float df0 = qv.x - xv.x, df1 = qv.y - xv.y;
            float df2 = qv.z - xv.z, df3 = qv.w - xv.w;
            lsum = fmaf(df0, df0, lsum); lsum = fmaf(df1, df1, lsum);
            lsum = fmaf(df2, df2, lsum); lsum = fmaf(df3, df3, lsum);
            float4 o = {xv.x + df0, xv.y + df1, xv.z + df2, xv.w + df3};
            reinterpret_cast<float4*>(orow)[i] = o;
        }
        if (half == 0) out[(size_t)N_ROWS * DIM + row] = (float)idx;
    }
    #pragma unroll
    for (int off = 32; off > 0; off >>= 1) lsum += __shfl_down(lsum, off, 64);
    if (lane == 0) atomicAdd(loss, lsum);
}

// exact np-chain re-scan for flagged rows: one wave per row, first-min over all K
__global__ void vq_fixup(const float* __restrict__ x, const float* __restrict__ emb,
                         const float* __restrict__ esq,
                         const unsigned int* __restrict__ cnt,
                         const unsigned int* __restrict__ list,
                         float* __restrict__ out, float* __restrict__ loss) {
#pragma clang fp contract(off)
    const int lane = threadIdx.x & 63;
    const int wid = (blockIdx.x * blockDim.x + threadIdx.x) >> 6;
    const int nw = (256 * 256) >> 6;
    unsigned count = *cnt;
    if (count > LIST_CAP) count = LIST_CAP;
    for (unsigned i = wid; i < count; i += nw) {
        const int row = (int)list[i];
        float xv[DIM];
        const float4* xp = reinterpret_cast<const float4*>(x + (size_t)row * DIM);
        #pragma unroll
        for (int q = 0; q < 16; ++q) {
            float4 v = xp[q];
            xv[4*q+0] = v.x; xv[4*q+1] = v.y; xv[4*q+2] = v.z; xv[4*q+3] = v.w;
        }
        float xsq;
        {   // np-exact xsq
            float xx[DIM];
            #pragma unroll
            for (int d = 0; d < DIM; ++d) xx[d] = xv[d] * xv[d];
            float r[8];
            #pragma unroll
            for (int j = 0; j < 8; ++j) r[j] = xx[j];
            #pragma unroll
            for (int ii = 8; ii < DIM; ii += 8)
                #pragma unroll
                for (int j = 0; j < 8; ++j) r[j] = r[j] + xx[ii + j];
            xsq = ((r[0]+r[1]) + (r[2]+r[3])) + ((r[4]+r[5]) + (r[6]+r[7]));
        }
        float best = INFINITY; int bidx = 0x7fffffff;
        for (int t = 0; t < K_CODES / 64; ++t) {
            const int k = lane + t * 64;   // ascending per lane
            const float* ek = emb + (size_t)k * DIM;
            float a0 = 0.f, a1 = 0.f, a2 = 0.f, a3 = 0.f;
            #pragma unroll
            for (int c = 0; c < DIM; c += 16)
                #pragma unroll
                for (int b = 12; b >= 0; b -= 4) {   // np block order
                    const int d = c + b;
                    a0 = a0 + xv[d+0] * ek[d+0];
                    a1 = a1 + xv[d+1] * ek[d+1];
                    a2 = a2 + xv[d+2] * ek[d+2];
                    a3 = a3 + xv[d+3] * ek[d+3];
                }
            float dot = (a0 + a1) + (a2 + a3);
            float tt = xsq + esq[k];
            float dist = tt - 2.0f * dot;
            if (dist < best) { best = dist; bidx = k; }
        }
        #pragma unroll
        for (int m = 1; m < 64; m <<= 1) {   // lexicographic (dist, idx) min
            float ob = __shfl_xor(best, m, 64);
            int   oi = __shfl_xor(bidx, m, 64);
            if (ob < best || (ob == best && oi < bidx)) { best = ob; bidx = oi; }
        }
        const float xd = x[(size_t)row * DIM + lane];
        const float qd = emb[(size_t)bidx * DIM + lane];
        const float df = qd - xd;
        out[(size_t)row * DIM + lane] = xd + df;
        if (lane == 0) out[(size_t)N_ROWS * DIM + row] = (float)bidx;
        float l2 = df * df;
        #pragma unroll
        for (int off = 32; off > 0; off >>= 1) l2 += __shfl_down(l2, off, 64);
        if (lane == 0) atomicAdd(loss, l2);
    }
}

__global__ void vq_final(const float* __restrict__ loss_acc, float* __restrict__ out_loss) {
    if (threadIdx.x == 0 && blockIdx.x == 0)
        out_loss[0] = loss_acc[0] / (float)((size_t)N_ROWS * DIM);
}

extern "C" void kernel_launch(void* const* d_in, const int* in_sizes, int n_in,
                              void* d_out, int out_size, void* d_ws, size_t ws_size,
                              hipStream_t stream) {
    const float* x   = (const float*)d_in[0];
    const float* emb = (const float*)d_in[1];
    float* out = (float*)d_out;

    unsigned int* cnt  = (unsigned int*)d_ws;
    float* loss        = (float*)d_ws + 1;
    float* esq         = (float*)d_ws + 4;
    unsigned short* wsB = (unsigned short*)((char*)d_ws + 8192);
    unsigned int* list = (unsigned int*)((char*)d_ws + 8192 + 524288);

    vq_prep<<<dim3(4), dim3(256), 0, stream>>>(emb, esq, wsB, cnt, loss);
    vq_mfma<<<dim3(N_ROWS / 128), dim3(256), 0, stream>>>(x, emb, esq, wsB, out,
                                                          cnt, list, loss);
    vq_fixup<<<dim3(256), dim3(256), 0, stream>>>(x, emb, esq, cnt, list, out, loss);
    vq_final<<<dim3(1), dim3(1), 0, stream>>>(loss, out + (size_t)N_ROWS * DIM + N_ROWS);
}

// Round 8
// 183.949 us; speedup vs baseline: 12.1821x; 1.3040x over previous
//
#include <hip/hip_runtime.h>
#include <hip/hip_bf16.h>

#define N_ROWS 131072
#define DIM 64
#define K_CODES 1024
#define NTILES 64
#define MARGIN 4e-5f
#define LIST_CAP 65536

typedef short short8 __attribute__((ext_vector_type(8)));
typedef float f32x4 __attribute__((ext_vector_type(4)));

__device__ __forceinline__ unsigned short f2bf(float f) {
    unsigned u = __float_as_uint(f);
    return (unsigned short)((u + 0x7fffu + ((u >> 16) & 1u)) >> 16);  // RNE
}
__device__ __forceinline__ float bf2f(unsigned short h) {
    return __uint_as_float(((unsigned)h) << 16);
}

// ws: byte 0: cnt u32, byte 4: loss f32, float idx 4..1027: esq,
//     byte 8192: B panel 256KB (64 tiles x 4 chunks x 64 lanes x 8 bf16),
//     byte 270336: fixup list u32[65536]

// prep: thread t = (k, c): k = code, c = chunk in {eh0, eh1, el0, el1}.
// chunk covers dims off=(c&1)*32 .. +31; sel = c>>1 (0 = hi, 1 = lo).
// lane l = g*16 + (k&15) holds elems j=0..7 -> value src[off + g*8 + j].
__global__ void vq_prep(const float* __restrict__ emb, float* __restrict__ esq,
                        unsigned short* __restrict__ wsB,
                        unsigned int* __restrict__ cnt, float* __restrict__ loss) {
#pragma clang fp contract(off)
    const int t = blockIdx.x * blockDim.x + threadIdx.x;
    if (t == 0) { *cnt = 0u; *loss = 0.f; }
    const int k = t >> 2, c = t & 3;
    if (k >= K_CODES) return;
    const float* e = emb + (size_t)k * DIM;

    if (c == 0) {   // np-exact esq (elementwise square, pairwise 8-acc chain)
        float ee[DIM];
        #pragma unroll
        for (int d = 0; d < DIM; ++d) { float v = e[d]; ee[d] = v * v; }
        float r[8];
        #pragma unroll
        for (int j = 0; j < 8; ++j) r[j] = ee[j];
        #pragma unroll
        for (int i = 8; i < DIM; i += 8)
            #pragma unroll
            for (int j = 0; j < 8; ++j) r[j] = r[j] + ee[i + j];
        esq[k] = ((r[0]+r[1]) + (r[2]+r[3])) + ((r[4]+r[5]) + (r[6]+r[7]));
    }

    const int off = (c & 1) * 32, sel = c >> 1;
    unsigned short val[32];
    #pragma unroll
    for (int j = 0; j < 32; ++j) {
        float v = e[off + j];
        unsigned short h = f2bf(v);
        val[j] = sel ? f2bf(v - bf2f(h)) : h;
    }
    const int tile = k >> 4, n = k & 15;
    #pragma unroll
    for (int g = 0; g < 4; ++g) {
        short8 s;
        #pragma unroll
        for (int j = 0; j < 8; ++j) s[j] = (short)val[g*8 + j];
        *reinterpret_cast<short8*>(wsB + ((size_t)((tile*4 + c)*64 + g*16 + n)) * 8) = s;
    }
}

__global__ __launch_bounds__(256, 2) void vq_mfma(const float* __restrict__ x,
        const float* __restrict__ emb, const float* __restrict__ esq,
        const unsigned short* __restrict__ wsB, float* __restrict__ out,
        unsigned int* __restrict__ cnt, unsigned int* __restrict__ list,
        float* __restrict__ loss) {
    const int tid = threadIdx.x;
    const int lane = tid & 63;
    const int w = tid >> 6;
    const int g = lane >> 4, res = lane & 15;
    const int rowbase = blockIdx.x * 256 + w * 64;   // 64 rows per wave (4 rgs)

    // A-frags: lane holds row (rowbase + rg*16 + res), k-slots g*8+j
    // (mirrors B packing -> any shared internal k-permutation gives correct dot)
    short8 Ah[4][2], Al[4][2];
    #pragma unroll
    for (int rg = 0; rg < 4; ++rg) {
        const float* xr = x + (size_t)(rowbase + rg*16 + res) * DIM;
        #pragma unroll
        for (int h = 0; h < 2; ++h) {
            float4 v0 = *reinterpret_cast<const float4*>(xr + h*32 + g*8);
            float4 v1 = *reinterpret_cast<const float4*>(xr + h*32 + g*8 + 4);
            float xv[8] = {v0.x, v0.y, v0.z, v0.w, v1.x, v1.y, v1.z, v1.w};
            short8 sh, sl;
            #pragma unroll
            for (int j = 0; j < 8; ++j) {
                unsigned short hb = f2bf(xv[j]);
                sh[j] = (short)hb;
                sl[j] = (short)f2bf(xv[j] - bf2f(hb));
            }
            Ah[rg][h] = sh; Al[rg][h] = sl;
        }
    }

    float b1[16], b2[16]; int bi[16];
    #pragma unroll
    for (int s = 0; s < 16; ++s) { b1[s] = 1e30f; b2[s] = 1e30f; bi[s] = 0; }

    auto loadB = [&](short8* Bd, int ct) {
        const unsigned short* bp = wsB + ((size_t)(ct*4)*64 + lane) * 8;
        #pragma unroll
        for (int c = 0; c < 4; ++c)
            Bd[c] = *reinterpret_cast<const short8*>(bp + (size_t)c * 64 * 8);
    };

    auto compute = [&](int ct, const short8* B) {
        const float esqv = esq[ct*16 + res];
        const int kcur = ct*16 + res;
        #pragma unroll
        for (int rg = 0; rg < 4; ++rg) {
            f32x4 acc = {0.f, 0.f, 0.f, 0.f};
            acc = __builtin_amdgcn_mfma_f32_16x16x32_bf16(Ah[rg][0], B[0], acc, 0,0,0); // hh
            acc = __builtin_amdgcn_mfma_f32_16x16x32_bf16(Ah[rg][1], B[1], acc, 0,0,0);
            acc = __builtin_amdgcn_mfma_f32_16x16x32_bf16(Ah[rg][0], B[2], acc, 0,0,0); // hl
            acc = __builtin_amdgcn_mfma_f32_16x16x32_bf16(Ah[rg][1], B[3], acc, 0,0,0);
            acc = __builtin_amdgcn_mfma_f32_16x16x32_bf16(Al[rg][0], B[0], acc, 0,0,0); // lh
            acc = __builtin_amdgcn_mfma_f32_16x16x32_bf16(Al[rg][1], B[1], acc, 0,0,0);
            #pragma unroll
            for (int r = 0; r < 4; ++r) {
                float v = fmaf(-2.0f, acc[r], esqv);  // d~ = esq - 2*dot
                const int s = rg*4 + r;
                bool lt = v < b1[s];
                b2[s] = fminf(fmaxf(v, b1[s]), b2[s]);  // med3: new runner-up
                b1[s] = fminf(v, b1[s]);
                bi[s] = lt ? kcur : bi[s];
            }
        }
    };

    short8 BA[4], BB[4];
    loadB(BA, 0);
    for (int ct = 0; ct < NTILES; ct += 2) {
        loadB(BB, ct + 1);
        compute(ct, BA);
        loadB(BA, (ct + 2) & 63);   // ct=62 reloads tile 0: unused, avoids branch
        compute(ct + 1, BB);
    }

    // top-2 merge across the 16 code-residue lanes
    #pragma unroll
    for (int m = 1; m < 16; m <<= 1) {
        #pragma unroll
        for (int s = 0; s < 16; ++s) {
            float ob1 = __shfl_xor(b1[s], m, 64);
            float ob2 = __shfl_xor(b2[s], m, 64);
            int   obi = __shfl_xor(bi[s], m, 64);
            float nb2 = fminf(fmaxf(b1[s], ob1), fminf(b2[s], ob2));
            bi[s] = (ob1 < b1[s]) ? obi : bi[s];
            b1[s] = fminf(b1[s], ob1);
            b2[s] = nb2;
        }
    }

    __shared__ int s_idx[256];
    __shared__ int s_flag[256];
    if (res == 0) {
        #pragma unroll
        for (int s = 0; s < 16; ++s) {   // row_local = w*64 + rg*16 + g*4 + r
            const int rl = w*64 + (s >> 2)*16 + g*4 + (s & 3);
            s_idx[rl] = bi[s];
            s_flag[rl] = (b2[s] - b1[s] < MARGIN) ? 1 : 0;
        }
    }
    __syncthreads();

    // epilogue: one thread per row
    const int row = blockIdx.x * 256 + tid;
    const int idx = s_idx[tid];
    float lsum = 0.f;
    if (s_flag[tid]) {
        unsigned slot = atomicAdd(cnt, 1u);
        if (slot < LIST_CAP) list[slot] = (unsigned)row;
    } else {
        const float* xr = x + (size_t)row * DIM;
        const float* qr = emb + (size_t)idx * DIM;
        float* orow = out + (size_t)row * DIM;
        #pragma unroll
        for (int i = 0; i < 16; ++i) {
            float4 xv = reinterpret_cast<const float4*>(xr)[i];
            float4 qv = reinterpret_cast<const float4*>(qr)[i];
            float df0 = qv.x - xv.x, df1 = qv.y - xv.y;
            float df2 = qv.z - xv.z, df3 = qv.w - xv.w;
            lsum = fmaf(df0, df0, lsum); lsum = fmaf(df1, df1, lsum);
            lsum = fmaf(df2, df2, lsum); lsum = fmaf(df3, df3, lsum);
            float4 o = {xv.x + df0, xv.y + df1, xv.z + df2, xv.w + df3};
            reinterpret_cast<float4*>(orow)[i] = o;
        }
        out[(size_t)N_ROWS * DIM + row] = (float)idx;
    }
    #pragma unroll
    for (int off = 32; off > 0; off >>= 1) lsum += __shfl_down(lsum, off, 64);
    if (lane == 0) atomicAdd(loss, lsum);
}

// exact np-chain re-scan for flagged rows: one wave per row, first-min over all K
__global__ void vq_fixup(const float* __restrict__ x, const float* __restrict__ emb,
                         const float* __restrict__ esq,
                         const unsigned int* __restrict__ cnt,
                         const unsigned int* __restrict__ list,
                         float* __restrict__ out, float* __restrict__ loss) {
#pragma clang fp contract(off)
    const int lane = threadIdx.x & 63;
    const int wid = (blockIdx.x * blockDim.x + threadIdx.x) >> 6;
    const int nw = (256 * 256) >> 6;
    unsigned count = *cnt;
    if (count > LIST_CAP) count = LIST_CAP;
    for (unsigned i = wid; i < count; i += nw) {
        const int row = (int)list[i];
        float xv[DIM];
        const float4* xp = reinterpret_cast<const float4*>(x + (size_t)row * DIM);
        #pragma unroll
        for (int q = 0; q < 16; ++q) {
            float4 v = xp[q];
            xv[4*q+0] = v.x; xv[4*q+1] = v.y; xv[4*q+2] = v.z; xv[4*q+3] = v.w;
        }
        float xsq;
        {   // np-exact xsq
            float xx[DIM];
            #pragma unroll
            for (int d = 0; d < DIM; ++d) xx[d] = xv[d] * xv[d];
            float r[8];
            #pragma unroll
            for (int j = 0; j < 8; ++j) r[j] = xx[j];
            #pragma unroll
            for (int ii = 8; ii < DIM; ii += 8)
                #pragma unroll
                for (int j = 0; j < 8; ++j) r[j] = r[j] + xx[ii + j];
            xsq = ((r[0]+r[1]) + (r[2]+r[3])) + ((r[4]+r[5]) + (r[6]+r[7]));
        }
        float best = INFINITY; int bidx = 0x7fffffff;
        for (int t = 0; t < K_CODES / 64; ++t) {
            const int k = lane + t * 64;   // ascending per lane
            const float* ek = emb + (size_t)k * DIM;
            float a0 = 0.f, a1 = 0.f, a2 = 0.f, a3 = 0.f;
            #pragma unroll
            for (int c = 0; c < DIM; c += 16)
                #pragma unroll
                for (int b = 12; b >= 0; b -= 4) {   // np block order
                    const int d = c + b;
                    a0 = a0 + xv[d+0] * ek[d+0];
                    a1 = a1 + xv[d+1] * ek[d+1];
                    a2 = a2 + xv[d+2] * ek[d+2];
                    a3 = a3 + xv[d+3] * ek[d+3];
                }
            float dot = (a0 + a1) + (a2 + a3);
            float tt = xsq + esq[k];
            float dist = tt - 2.0f * dot;
            if (dist < best) { best = dist; bidx = k; }
        }
        #pragma unroll
        for (int m = 1; m < 64; m <<= 1) {   // lexicographic (dist, idx) min
            float ob = __shfl_xor(best, m, 64);
            int   oi = __shfl_xor(bidx, m, 64);
            if (ob < best || (ob == best && oi < bidx)) { best = ob; bidx = oi; }
        }
        const float xd = x[(size_t)row * DIM + lane];
        const float qd = emb[(size_t)bidx * DIM + lane];
        const float df = qd - xd;
        out[(size_t)row * DIM + lane] = xd + df;
        if (lane == 0) out[(size_t)N_ROWS * DIM + row] = (float)bidx;
        float l2 = df * df;
        #pragma unroll
        for (int off = 32; off > 0; off >>= 1) l2 += __shfl_down(l2, off, 64);
        if (lane == 0) atomicAdd(loss, l2);
    }
}

__global__ void vq_final(const float* __restrict__ loss_acc, float* __restrict__ out_loss) {
    if (threadIdx.x == 0 && blockIdx.x == 0)
        out_loss[0] = loss_acc[0] / (float)((size_t)N_ROWS * DIM);
}

extern "C" void kernel_launch(void* const* d_in, const int* in_sizes, int n_in,
                              void* d_out, int out_size, void* d_ws, size_t ws_size,
                              hipStream_t stream) {
    const float* x   = (const float*)d_in[0];
    const float* emb = (const float*)d_in[1];
    float* out = (float*)d_out;

    unsigned int* cnt  = (unsigned int*)d_ws;
    float* loss        = (float*)d_ws + 1;
    float* esq         = (float*)d_ws + 4;
    unsigned short* wsB = (unsigned short*)((char*)d_ws + 8192);
    unsigned int* list = (unsigned int*)((char*)d_ws + 270336);

    vq_prep<<<dim3(16), dim3(256), 0, stream>>>(emb, esq, wsB, cnt, loss);
    vq_mfma<<<dim3(N_ROWS / 256), dim3(256), 0, stream>>>(x, emb, esq, wsB, out,
                                                          cnt, list, loss);
    vq_fixup<<<dim3(256), dim3(256), 0, stream>>>(x, emb, esq, cnt, list, out, loss);
    vq_final<<<dim3(1), dim3(1), 0, stream>>>(loss, out + (size_t)N_ROWS * DIM + N_ROWS);
}